// Round 7
// baseline (167.753 us; speedup 1.0000x reference)
//
#include <hip/hip_runtime.h>
#include <cstdint>
#include <cstddef>

// ---------------------------------------------------------------------------
// Fused causal attention block: QKV proj (+RoPE) -> MFMA flash attn -> out proj
// B=2 T=2048 C=1024 H=16 HD=64. Inputs fp32, output fp32, internal bf16 MFMA.
// R18 = R17 + attn micro-scheduling (structure identical):
//  (1) staging commit (vmcnt drain + ds_writes) moved BEFORE the PV MFMAs --
//      its latency hides under PV instead of sitting on the barrier path;
//  (2) s_setprio(1)/(0) around the MFMA clusters (T5, +4-7% attn measured);
//  (3) softmax denom via 2 ones x P MFMAs into NAMED f32x16 accl (replaces
//      16 serial VALU adds/step + epilogue shfl; R12-validated pattern; all
//      indices compile-time constant -> no scratch. accl[0] = full col sum).
// R17/R16: 32x32x16 inner loop, QBLK=64, 256-thr blocks, wave (kh,qh) splits
// 64 keys/step x 64 q; grid (32,32)=1024 = 4 blocks/CU = 16 waves/CU;
// stride-72 conflict-free LDS; named staging regs; 66-step/CU qt map;
// cvt_pk+permlane pack; dbuf 1 barrier/step; end cross-kh combine in dead Ks.
// Known floor in dur_us: harness 0xAA ws-poison fill ~43us + ~10us gaps.
// ws (bf16 elems): xb@0 (4M, reused as swizzled attn-out), QK@4M (8M, stride
// 2048), Vt@12M (4M), Wqkv@16M (3M), Wob@19M (1M), cs-table@20M (512KB).
// ---------------------------------------------------------------------------

typedef __bf16 bf16;
typedef float  f32x4  __attribute__((ext_vector_type(4)));
typedef float  f32x16 __attribute__((ext_vector_type(16)));
typedef __bf16 bf16x4 __attribute__((ext_vector_type(4)));
typedef __bf16 bf16x8 __attribute__((ext_vector_type(8)));

constexpr int Bb = 2, Tt = 2048, Cc = 1024, Hh = 16;
constexpr int Mrows = Bb * Tt;          // 4096
constexpr int NT = Tt / 64;             // 32 key tiles
constexpr int LDS_ = 72;                // attention LDS stride

#define GLOAD_LDS16(gp, lp)                                                      \
    __builtin_amdgcn_global_load_lds(                                            \
        (const __attribute__((address_space(1))) void*)(gp),                     \
        (__attribute__((address_space(3))) void*)(lp), 16, 0, 0)

// 4x4 transpose across lanes (low 2 bits of l16) x regs
#define QUAD_T(v0, v1, v2, v3, c2)                                               \
    {                                                                            \
        float e0 = (c2 & 1) ? v0 : v1, e1 = (c2 & 1) ? v2 : v3;                  \
        e0 = __shfl_xor(e0, 1); e1 = __shfl_xor(e1, 1);                          \
        if (c2 & 1) { v0 = e0; v2 = e1; } else { v1 = e0; v3 = e1; }             \
        float f0 = (c2 & 2) ? v0 : v2, f1 = (c2 & 2) ? v1 : v3;                  \
        f0 = __shfl_xor(f0, 2); f1 = __shfl_xor(f1, 2);                          \
        if (c2 & 2) { v0 = f0; v1 = f1; } else { v2 = f0; v3 = f1; }             \
    }

__device__ inline unsigned pkb(float a, float b)
{
    unsigned r;
    asm("v_cvt_pk_bf16_f32 %0, %1, %2" : "=v"(r) : "v"(a), "v"(b));
    return r;
}

// ---- convert: fp32 -> bf16 into swizzled tiles; Wq pre-scaled; cs packing ----
__global__ __launch_bounds__(256) void convert_k(const float* __restrict__ x,
                                                 const float* __restrict__ Wq,
                                                 const float* __restrict__ Wk,
                                                 const float* __restrict__ Wv,
                                                 const float* __restrict__ Wo,
                                                 const float* __restrict__ cosb,
                                                 const float* __restrict__ sinb,
                                                 bf16* __restrict__ xb,
                                                 bf16* __restrict__ Wqkv,
                                                 bf16* __restrict__ Wob,
                                                 float2* __restrict__ cs)
{
    if (blockIdx.x >= 4096) {           // cs-table packing: 65536 (t,p) pairs
        int pi = ((blockIdx.x - 4096) * 256 + threadIdx.x) * 8;
#pragma unroll
        for (int u = 0; u < 8; ++u)
            cs[pi + u] = float2{cosb[pi + u], sinb[pi + u]};
        return;
    }
    uint32_t id = blockIdx.x * 256 + threadIdx.x;      // one 16-B dst chunk
    const float* src; bf16* dst; float sc = 1.0f;
    if (id < 524288u) {                                // xb: 32rb x 16kb x 1024
        uint32_t tile = id >> 10, slot = id & 1023;
        uint32_t row = (tile >> 4) * 128 + (slot >> 9) * 64 +
                       ((slot >> 6) & 3) * 16 + (slot & 15);
        uint32_t k = (tile & 15) * 64 + ((slot >> 8) & 1) * 32 + ((slot >> 4) & 3) * 8;
        src = x + (size_t)row * 1024 + k;
        dst = xb + (size_t)id * 8;
    } else if (id < 917504u) {                         // Wqkv: 24cb x 16kb x 1024
        uint32_t t2 = id - 524288u;
        uint32_t tile = t2 >> 10, slot = t2 & 1023;
        uint32_t n = (tile >> 4) * 128 + (slot >> 9) * 64 +
                     ((slot >> 6) & 3) * 16 + (slot & 15);
        uint32_t k = (tile & 15) * 64 + ((slot >> 8) & 1) * 32 + ((slot >> 4) & 3) * 8;
        if (n < 1024)      { src = Wq + (size_t)n * 1024 + k;
                             sc = 0.125f * 1.44269504088896f; }
        else if (n < 2048)   src = Wk + (size_t)(n - 1024) * 1024 + k;
        else                 src = Wv + (size_t)(n - 2048) * 1024 + k;
        dst = Wqkv + (size_t)t2 * 8;
    } else {                                           // Wob: 16cb x 16kb x 512
        uint32_t t3 = id - 917504u;
        uint32_t tile = t3 >> 9, slot = t3 & 511;
        uint32_t n = (tile >> 4) * 64 + (slot >> 8) * 32 +
                     ((slot >> 6) & 1) * 16 + (slot & 15);
        uint32_t k = (tile & 15) * 64 + ((slot >> 7) & 1) * 32 + ((slot >> 4) & 3) * 8;
        src = Wo + (size_t)n * 1024 + k;
        dst = Wob + (size_t)t3 * 8;
    }
    float4 v0 = *(const float4*)(src);
    float4 v1 = *(const float4*)(src + 4);
    bf16x8 t;
    t[0] = (bf16)(v0.x*sc); t[1] = (bf16)(v0.y*sc); t[2] = (bf16)(v0.z*sc); t[3] = (bf16)(v0.w*sc);
    t[4] = (bf16)(v1.x*sc); t[5] = (bf16)(v1.y*sc); t[6] = (bf16)(v1.z*sc); t[7] = (bf16)(v1.w*sc);
    *(bf16x8*)dst = t;
}

// ---- QKV GEMM [4096x3072x1024], swizzled-tile inputs, RoPE/Vt epilogue ----
__global__ __launch_bounds__(256) void gemm_qkv(const bf16* __restrict__ A,
                                                const bf16* __restrict__ W,
                                                bf16* __restrict__ QK,
                                                bf16* __restrict__ Vt,
                                                const float2* __restrict__ cs)
{
    __shared__ bf16 As[8192];
    __shared__ bf16 Ws[8192];
    const int tid  = threadIdx.x;
    const int lane = tid & 63, wave = tid >> 6;
    const int rhw = wave >> 1, chw = wave & 1;
    const int wr = rhw * 64, wc = chw * 64;
    const int l16 = lane & 15, lq = lane >> 4;
    const int row0 = blockIdx.x * 128, col0 = blockIdx.y * 128;

    f32x4 acc[4][4];
#pragma unroll
    for (int i = 0; i < 4; ++i)
#pragma unroll
        for (int j = 0; j < 4; ++j) acc[i][j] = f32x4{0.f, 0.f, 0.f, 0.f};

    const bf16* At = A + (size_t)blockIdx.x * 16 * 8192;
    const bf16* Wt = W + (size_t)blockIdx.y * 16 * 8192;

    for (int kb = 0; kb < 16; ++kb) {
        const bf16* at = At + kb * 8192;
        const bf16* wt = Wt + kb * 8192;
#pragma unroll
        for (int rnd = 0; rnd < 4; ++rnd) {
            const int seg = rnd * 4 + wave;            // contiguous 1KB segment
            GLOAD_LDS16(at + seg * 512 + lane * 8, &As[seg * 512]);
            GLOAD_LDS16(wt + seg * 512 + lane * 8, &Ws[seg * 512]);
        }
        __syncthreads();
#pragma unroll
        for (int ks = 0; ks < 2; ++ks) {
            bf16x8 af[4], bfr[4];
#pragma unroll
            for (int i = 0; i < 4; ++i)
                af[i] = *(const bf16x8*)(&As[(rhw * 512 + ks * 256 + i * 64 + lq * 16 + l16) * 8]);
#pragma unroll
            for (int j = 0; j < 4; ++j)
                bfr[j] = *(const bf16x8*)(&Ws[(chw * 512 + ks * 256 + j * 64 + lq * 16 + l16) * 8]);
#pragma unroll
            for (int i = 0; i < 4; ++i)
#pragma unroll
                for (int j = 0; j < 4; ++j)
                    acc[i][j] = __builtin_amdgcn_mfma_f32_16x16x32_bf16(
                        af[i], bfr[j], acc[i][j], 0, 0, 0);
        }
        __syncthreads();
    }

    const int c2 = l16 & 3, g4 = (l16 >> 2) * 4;
    if (blockIdx.y < 16) {
        // Q/K tile: quad-transpose -> lane owns 1 row x 4 cols; RoPE intra-lane
#pragma unroll
        for (int i = 0; i < 4; ++i)
#pragma unroll
            for (int j = 0; j < 4; ++j) {
                float v0 = acc[i][j][0], v1 = acc[i][j][1];
                float v2 = acc[i][j][2], v3 = acc[i][j][3];
                QUAD_T(v0, v1, v2, v3, c2);
                const int row = row0 + wr + i * 16 + lq * 4 + c2;
                const int t   = row & (Tt - 1);
                const int colb = wc + j * 16 + g4;
                const int p0   = (colb & 63) >> 1;
                float4 cp = *(const float4*)(&cs[t * 32 + p0]);  // (c0,s0,c1,s1)
                bf16x4 pk;
                pk[0] = (bf16)(v0 * cp.x - v1 * cp.y);
                pk[1] = (bf16)(v0 * cp.y + v1 * cp.x);
                pk[2] = (bf16)(v2 * cp.z - v3 * cp.w);
                pk[3] = (bf16)(v2 * cp.w + v3 * cp.z);
                *(bf16x4*)(&QK[(size_t)row * 2048 + col0 + colb]) = pk;
            }
    } else {
        // V tile: transposed store into Vt[bh][d][t]
#pragma unroll
        for (int i = 0; i < 4; ++i)
#pragma unroll
            for (int j = 0; j < 4; ++j) {
                const int dfull = col0 - 2048 + wc + j * 16 + l16;
                const int h = dfull >> 6, d = dfull & 63;
                const int row = row0 + wr + i * 16 + lq * 4;
                const int b = row >> 11, t = row & (Tt - 1);
                bf16x4 pk;
                pk[0] = (bf16)acc[i][j][0]; pk[1] = (bf16)acc[i][j][1];
                pk[2] = (bf16)acc[i][j][2]; pk[3] = (bf16)acc[i][j][3];
                *(bf16x4*)(&Vt[((size_t)(b * 16 + h) * 64 + d) * (size_t)Tt + t]) = pk;
            }
    }
}

// ---- O GEMM: 128x64 tiles, swizzled A (from attn) + swizzled Wob, fp32 out --
__global__ __launch_bounds__(256) void gemm_o(const bf16* __restrict__ A,
                                              const bf16* __restrict__ W,
                                              float* __restrict__ Out)
{
    __shared__ bf16 As[8192];
    __shared__ bf16 Ws[4096];
    const int tid  = threadIdx.x;
    const int lane = tid & 63, wave = tid >> 6;
    const int rhw = wave >> 1, chw = wave & 1;
    const int wr = rhw * 64, wc = chw * 32;
    const int l16 = lane & 15, lq = lane >> 4;
    const int row0 = blockIdx.x * 128, col0 = blockIdx.y * 64;

    f32x4 acc[4][2];
#pragma unroll
    for (int i = 0; i < 4; ++i)
#pragma unroll
        for (int j = 0; j < 2; ++j) acc[i][j] = f32x4{0.f, 0.f, 0.f, 0.f};

    const bf16* At = A + (size_t)blockIdx.x * 16 * 8192;
    const bf16* Wt = W + (size_t)blockIdx.y * 16 * 4096;

    for (int kb = 0; kb < 16; ++kb) {
        const bf16* at = At + kb * 8192;
        const bf16* wt = Wt + kb * 4096;
#pragma unroll
        for (int rnd = 0; rnd < 4; ++rnd) {
            const int seg = rnd * 4 + wave;
            GLOAD_LDS16(at + seg * 512 + lane * 8, &As[seg * 512]);
        }
#pragma unroll
        for (int rnd = 0; rnd < 2; ++rnd) {
            const int seg = rnd * 4 + wave;
            GLOAD_LDS16(wt + seg * 512 + lane * 8, &Ws[seg * 512]);
        }
        __syncthreads();
#pragma unroll
        for (int ks = 0; ks < 2; ++ks) {
            bf16x8 af[4], bfr[2];
#pragma unroll
            for (int i = 0; i < 4; ++i)
                af[i] = *(const bf16x8*)(&As[(rhw * 512 + ks * 256 + i * 64 + lq * 16 + l16) * 8]);
#pragma unroll
            for (int j = 0; j < 2; ++j)
                bfr[j] = *(const bf16x8*)(&Ws[(chw * 256 + ks * 128 + j * 64 + lq * 16 + l16) * 8]);
#pragma unroll
            for (int i = 0; i < 4; ++i)
#pragma unroll
                for (int j = 0; j < 2; ++j)
                    acc[i][j] = __builtin_amdgcn_mfma_f32_16x16x32_bf16(
                        af[i], bfr[j], acc[i][j], 0, 0, 0);
        }
        __syncthreads();
    }
    const int c2 = l16 & 3, g4 = (l16 >> 2) * 4;
#pragma unroll
    for (int i = 0; i < 4; ++i)
#pragma unroll
        for (int j = 0; j < 2; ++j) {
            float v0 = acc[i][j][0], v1 = acc[i][j][1];
            float v2 = acc[i][j][2], v3 = acc[i][j][3];
            QUAD_T(v0, v1, v2, v3, c2);
            const int row = row0 + wr + i * 16 + lq * 4 + c2;
            const int col = col0 + wc + j * 16 + g4;
            *(float4*)(&Out[(size_t)row * Cc + col]) = float4{v0, v1, v2, v3};
        }
}

// ---- MFMA flash attention, 32x32x16 shape, QBLK=64, 256 threads = 4 waves:
// wave (kh,qh) owns q-cols qh*32+[0,32) x keys kh*32+[0,32) of each 64-key
// step. 4 blocks/CU = 16 waves/CU. dbuf LDS 1 barrier/step, R12 qt map,
// named regs only. Commit-before-PV, setprio around MFMA, l via ones-MFMA.
__global__ __launch_bounds__(256, 4) void attn_k(const bf16* __restrict__ QK,
                                                 const bf16* __restrict__ Vt,
                                                 bf16* __restrict__ O)
{
    __shared__ bf16 Ks[2][64 * LDS_];
    __shared__ bf16 Vs[2][64 * LDS_];
    const int tid = threadIdx.x;
    const int wv = tid >> 6, lane = tid & 63;
    const int l31 = lane & 31, hf = lane >> 5;
    const int qh = wv & 1, kh = wv >> 1;
    // grid (32,32)=1024 blocks, 4/CU. id&7 ~ XCD; 4 bh per XCD.
    // Rounds rnd4=id>>8 give qt = {31-s,16+s,15-s,s}: every CU's 4 resident
    // blocks sum to (32-s)+(17+s)+(16-s)+(1+s) = 66 key-steps.
    const int id = blockIdx.y * gridDim.x + blockIdx.x;
    const int bh = (id & 7) * 4 + ((id >> 3) & 3);
    const int s8 = (id >> 5) & 7, rnd4 = id >> 8;
    const int qt = (rnd4 == 0) ? 31 - s8 : (rnd4 == 1) ? 16 + s8
                 : (rnd4 == 2) ? 15 - s8 : s8;
    const int b = bh >> 4, h = bh & 15;
    const int kr = tid >> 2, c0 = (tid & 3) * 16;       // staging coords

    const bf16* kcol = QK + 1024 + (size_t)(b * Tt + kr) * 2048 + h * 64 + c0;
    const bf16* vcol = Vt + ((size_t)bh * 64 + kr) * Tt + c0;

    // Q B-frags: lane = q-col (l31) of this wave's 32; k(d) = 16*kc + 8*hf + j
    const int qglob = qt * 64 + qh * 32 + l31;
    const bf16* qp = QK + (size_t)(b * Tt + qglob) * 2048 + h * 64 + hf * 8;
    const bf16x8 qf0 = *(const bf16x8*)(qp);
    const bf16x8 qf1 = *(const bf16x8*)(qp + 16);
    const bf16x8 qf2 = *(const bf16x8*)(qp + 32);
    const bf16x8 qf3 = *(const bf16x8*)(qp + 48);

    bf16x8 onef;                                        // ones A-frag for l-sum
#pragma unroll
    for (int r = 0; r < 8; ++r) onef[r] = (bf16)1.0f;

    // prologue: tile 0 -> named regs -> buf 0 (Ks[key][d], Vs[d][key])
    uint4 ka0 = *(const uint4*)(kcol);
    uint4 ka1 = *(const uint4*)(kcol + 8);
    uint4 va0 = *(const uint4*)(vcol);
    uint4 va1 = *(const uint4*)(vcol + 8);
    {
        bf16* kd = &Ks[0][kr * LDS_ + c0];
        bf16* vd = &Vs[0][kr * LDS_ + c0];
        *(uint4*)(kd)     = ka0; *(uint4*)(kd + 8) = ka1;
        *(uint4*)(vd)     = va0; *(uint4*)(vd + 8) = va1;
    }
    __syncthreads();

    f32x16 o0, o1, accl;
#pragma unroll
    for (int r = 0; r < 16; ++r) { o0[r] = 0.f; o1[r] = 0.f; accl[r] = 0.f; }

    for (int t = 0; t <= qt; ++t) {
        const int cur = t & 1;
        if (t < qt) {                   // prefetch next tile into named regs
            const bf16* kn = kcol + (size_t)(t + 1) * 64 * 2048;
            const bf16* vn = vcol + (t + 1) * 64;
            ka0 = *(const uint4*)(kn); ka1 = *(const uint4*)(kn + 8);
            va0 = *(const uint4*)(vn); va1 = *(const uint4*)(vn + 8);
        }

        // S^T tile: keys kh*32+[0,32) x q. A = K rows, B = qf0..3 (K-dim 64)
        f32x16 s;
#pragma unroll
        for (int r = 0; r < 16; ++r) s[r] = 0.f;
        {
            const bf16* kb = &Ks[cur][(kh * 32 + l31) * LDS_ + hf * 8];
            bf16x8 a;
            __builtin_amdgcn_s_setprio(1);
            a = *(const bf16x8*)(kb);      s = __builtin_amdgcn_mfma_f32_32x32x16_bf16(a, qf0, s, 0, 0, 0);
            a = *(const bf16x8*)(kb + 16); s = __builtin_amdgcn_mfma_f32_32x32x16_bf16(a, qf1, s, 0, 0, 0);
            a = *(const bf16x8*)(kb + 32); s = __builtin_amdgcn_mfma_f32_32x32x16_bf16(a, qf2, s, 0, 0, 0);
            a = *(const bf16x8*)(kb + 48); s = __builtin_amdgcn_mfma_f32_32x32x16_bf16(a, qf3, s, 0, 0, 0);
            __builtin_amdgcn_s_setprio(0);
        }
        if (t == qt) {                  // causal mask, diagonal tile only
            const int kbase = t * 64 + kh * 32 + 4 * hf;
#pragma unroll
            for (int r = 0; r < 16; ++r) {
                const int key0 = kbase + (r & 3) + 8 * (r >> 2);
                if (key0 > qglob) s[r] = -1e30f;
            }
        }
        // exp2 (denominator comes from the ones-MFMA below, not VALU sums)
#pragma unroll
        for (int r = 0; r < 16; ++r)
            s[r] = exp2f(s[r]);
        // P^T C-frag -> PV B-frags (keys kh*32+16c+8hf+j): cvt_pk + permlane
        bf16x8 pb0, pb1;
        {
            unsigned X, Y, Z, W;
            union { unsigned u[4]; bf16x8 h; } tmp;
            X = pkb(s[0],  s[1]);  Y = pkb(s[2],  s[3]);
            Z = pkb(s[4],  s[5]);  W = pkb(s[6],  s[7]);
            asm("v_permlane32_swap_b32 %0, %1" : "+v"(X), "+v"(Z));
            asm("v_permlane32_swap_b32 %0, %1" : "+v"(Y), "+v"(W));
            tmp.u[0] = X; tmp.u[1] = Y; tmp.u[2] = Z; tmp.u[3] = W; pb0 = tmp.h;
            X = pkb(s[8],  s[9]);  Y = pkb(s[10], s[11]);
            Z = pkb(s[12], s[13]); W = pkb(s[14], s[15]);
            asm("v_permlane32_swap_b32 %0, %1" : "+v"(X), "+v"(Z));
            asm("v_permlane32_swap_b32 %0, %1" : "+v"(Y), "+v"(W));
            tmp.u[0] = X; tmp.u[1] = Y; tmp.u[2] = Z; tmp.u[3] = W; pb1 = tmp.h;
        }
        // commit prefetched tile to buf^1 EARLY: vmcnt drain + ds_writes
        // overlap with the PV MFMAs below instead of the barrier path.
        if (t < qt) {
            bf16* kd = &Ks[cur ^ 1][kr * LDS_ + c0];
            bf16* vd = &Vs[cur ^ 1][kr * LDS_ + c0];
            *(uint4*)(kd)     = ka0; *(uint4*)(kd + 8) = ka1;
            *(uint4*)(vd)     = va0; *(uint4*)(vd + 8) = va1;
        }
        // O^T partial += V^T[d, kh-keys] P^T ; l via ones x P (col sums,
        // replicated across rows -> accl[0] is the full per-wave denominator)
        {
            const bf16* vb0 = &Vs[cur][l31 * LDS_ + kh * 32 + hf * 8];
            const bf16* vb1 = &Vs[cur][(32 + l31) * LDS_ + kh * 32 + hf * 8];
            bf16x8 v;
            __builtin_amdgcn_s_setprio(1);
            accl = __builtin_amdgcn_mfma_f32_32x32x16_bf16(onef, pb0, accl, 0, 0, 0);
            accl = __builtin_amdgcn_mfma_f32_32x32x16_bf16(onef, pb1, accl, 0, 0, 0);
            v = *(const bf16x8*)(vb0);      o0 = __builtin_amdgcn_mfma_f32_32x32x16_bf16(v, pb0, o0, 0, 0, 0);
            v = *(const bf16x8*)(vb0 + 16); o0 = __builtin_amdgcn_mfma_f32_32x32x16_bf16(v, pb1, o0, 0, 0, 0);
            v = *(const bf16x8*)(vb1);      o1 = __builtin_amdgcn_mfma_f32_32x32x16_bf16(v, pb0, o1, 0, 0, 0);
            v = *(const bf16x8*)(vb1 + 16); o1 = __builtin_amdgcn_mfma_f32_32x32x16_bf16(v, pb1, o1, 0, 0, 0);
            __builtin_amdgcn_s_setprio(0);
        }
        __syncthreads();                // publish buf^1; all readers done
    }
    float lsum = accl[0];               // full col sum over this wave's keys

    // cross-kh combine: kh=1 writes partial O (64d x 32q f32) + l into dead
    // Ks (16.9KB f32 < 36.8KB) / Vs; kh=0 adds, divides, stores.
    float* fscr = (float*)(&Ks[0][0]);
    float* lscr = (float*)(&Vs[0][0]);
    if (kh == 1) {
        float* sb = fscr + qh * (64 * 33);
#pragma unroll
        for (int r = 0; r < 16; ++r) {
            const int d = (r & 3) + 8 * (r >> 2) + 4 * hf;
            sb[d * 33 + l31]        = o0[r];
            sb[(d + 32) * 33 + l31] = o1[r];
        }
        if (hf == 0) lscr[qh * 32 + l31] = lsum;
    }
    __syncthreads();
    if (kh == 0) {
        const float* sb = fscr + qh * (64 * 33);
#pragma unroll
        for (int r = 0; r < 16; ++r) {
            const int d = (r & 3) + 8 * (r >> 2) + 4 * hf;
            o0[r] += sb[d * 33 + l31];
            o1[r] += sb[(d + 32) * 33 + l31];
        }
        lsum += lscr[qh * 32 + l31];
        const float inv = 1.f / lsum;

        // store O in gemm_o's swizzled A layout.
        // 128-row tile index = qt>>1, rh = qt&1; row128 = rh*64 + qh*32 + l31;
        // d = 32*dt + 8*g + 4*hf + r.
        bf16* obase = O + ((size_t)(16 * b + (qt >> 1)) * 16 + h) * 8192;
        const int rh = qt & 1;
        const int slot_row = (lane & 15) | (((2 * qh + ((lane >> 4) & 1)) & 3) << 6) |
                             (rh << 9);
#pragma unroll
        for (int g = 0; g < 4; ++g) {
            bf16x4 w0, w1;
#pragma unroll
            for (int r = 0; r < 4; ++r) {
                w0[r] = (bf16)(o0[4 * g + r] * inv);
                w1[r] = (bf16)(o1[4 * g + r] * inv);
            }
            *(bf16x4*)(obase + (slot_row | (g << 4)) * 8 + 4 * hf) = w0;
            *(bf16x4*)(obase + (slot_row | (g << 4) | 256) * 8 + 4 * hf) = w1;
        }
    }
}

extern "C" void kernel_launch(void* const* d_in, const int* in_sizes, int n_in,
                              void* d_out, int out_size, void* d_ws, size_t ws_size,
                              hipStream_t stream)
{
    const float* x    = (const float*)d_in[0];
    const float* Wq   = (const float*)d_in[1];
    const float* Wk   = (const float*)d_in[2];
    const float* Wv   = (const float*)d_in[3];
    const float* Wo   = (const float*)d_in[4];
    const float* cosb = (const float*)d_in[5];
    const float* sinb = (const float*)d_in[6];

    constexpr size_t M1 = 1024 * 1024;
    bf16* base = (bf16*)d_ws;
    bf16*   xb   = base;                    //  0..4M   swizzled x; reused attn-out
    bf16*   QK   = base + 4 * M1;           //  4M..12M [4096][2048]
    bf16*   VtG  = base + 12 * M1;          // 12M..16M [32][64][2048]
    bf16*   Wqkv = base + 16 * M1;          // 16M..19M swizzled
    bf16*   Wob  = base + 19 * M1;          // 19M..20M swizzled (64-row tiles)
    float2* csT  = (float2*)(base + 20 * M1); // 512 KB
    bf16*   Ow   = xb;

    convert_k<<<4096 + 32, 256, 0, stream>>>(x, Wq, Wk, Wv, Wo, cosb, sinb,
                                             xb, Wqkv, Wob, csT);

    gemm_qkv<<<dim3(Mrows / 128, 3072 / 128), 256, 0, stream>>>(
        xb, Wqkv, QK, VtG, csT);

    attn_k<<<dim3(32, 32), 256, 0, stream>>>(QK, VtG, Ow);

    gemm_o<<<dim3(Mrows / 128, Cc / 64), 256, 0, stream>>>(Ow, Wob, (float*)d_out);
}

// Round 9
// 163.526 us; speedup vs baseline: 1.0258x; 1.0258x over previous
//
#include <hip/hip_runtime.h>
#include <cstdint>
#include <cstddef>

// ---------------------------------------------------------------------------
// Fused causal attention block: QKV proj (+RoPE) -> MFMA flash attn -> out proj
// B=2 T=2048 C=1024 H=16 HD=64. Inputs fp32, output fp32, internal bf16 MFMA.
// R20 = R17 (best measured, 166.5us, passed) + ONE change: exp2 via inline
// asm "v_exp_f32 ; s_nop 1" (unambiguous 2^x per ISA; s_nop covers the
// trans-op wait state the compiler can't insert around opaque asm). R19's
// EXP2F macro (builtin/OCML) broke numerics -> dropped entirely. R18's
// neutral micro-scheduling (setprio/commit-early/ones-MFMA denom) dropped.
// R17/R16: 32x32x16 inner loop, QBLK=64, 256-thr blocks, wave (kh,qh) splits
// 64 keys/step x 64 q; grid (32,32)=1024 = 4 blocks/CU = 16 waves/CU;
// stride-72 conflict-free LDS; named staging regs; 66-step/CU qt map;
// cvt_pk+permlane pack; dbuf 1 barrier/step; end cross-kh combine in dead Ks.
// Known floor in dur_us: harness 0xAA ws-poison fill ~43us + ~10us gaps.
// ws (bf16 elems): xb@0 (4M, reused as swizzled attn-out), QK@4M (8M, stride
// 2048), Vt@12M (4M), Wqkv@16M (3M), Wob@19M (1M), cs-table@20M (512KB).
// ---------------------------------------------------------------------------

typedef __bf16 bf16;
typedef float  f32x4  __attribute__((ext_vector_type(4)));
typedef float  f32x16 __attribute__((ext_vector_type(16)));
typedef __bf16 bf16x4 __attribute__((ext_vector_type(4)));
typedef __bf16 bf16x8 __attribute__((ext_vector_type(8)));

constexpr int Bb = 2, Tt = 2048, Cc = 1024, Hh = 16;
constexpr int Mrows = Bb * Tt;          // 4096
constexpr int NT = Tt / 64;             // 32 key tiles
constexpr int LDS_ = 72;                // attention LDS stride

#define GLOAD_LDS16(gp, lp)                                                      \
    __builtin_amdgcn_global_load_lds(                                            \
        (const __attribute__((address_space(1))) void*)(gp),                     \
        (__attribute__((address_space(3))) void*)(lp), 16, 0, 0)

// 4x4 transpose across lanes (low 2 bits of l16) x regs
#define QUAD_T(v0, v1, v2, v3, c2)                                               \
    {                                                                            \
        float e0 = (c2 & 1) ? v0 : v1, e1 = (c2 & 1) ? v2 : v3;                  \
        e0 = __shfl_xor(e0, 1); e1 = __shfl_xor(e1, 1);                          \
        if (c2 & 1) { v0 = e0; v2 = e1; } else { v1 = e0; v3 = e1; }             \
        float f0 = (c2 & 2) ? v0 : v2, f1 = (c2 & 2) ? v1 : v3;                  \
        f0 = __shfl_xor(f0, 2); f1 = __shfl_xor(f1, 2);                          \
        if (c2 & 2) { v0 = f0; v1 = f1; } else { v2 = f0; v3 = f1; }             \
    }

__device__ inline unsigned pkb(float a, float b)
{
    unsigned r;
    asm("v_cvt_pk_bf16_f32 %0, %1, %2" : "=v"(r) : "v"(a), "v"(b));
    return r;
}

// native 2^x: v_exp_f32 per cdna4_isa §3; s_nop 1 inside covers the
// trans-op -> VALU-read wait state (compiler can't see into the asm).
__device__ inline float ex2(float x)
{
    float r;
    asm("v_exp_f32 %0, %1\n\ts_nop 1" : "=v"(r) : "v"(x));
    return r;
}

// ---- convert: fp32 -> bf16 into swizzled tiles; Wq pre-scaled; cs packing ----
__global__ __launch_bounds__(256) void convert_k(const float* __restrict__ x,
                                                 const float* __restrict__ Wq,
                                                 const float* __restrict__ Wk,
                                                 const float* __restrict__ Wv,
                                                 const float* __restrict__ Wo,
                                                 const float* __restrict__ cosb,
                                                 const float* __restrict__ sinb,
                                                 bf16* __restrict__ xb,
                                                 bf16* __restrict__ Wqkv,
                                                 bf16* __restrict__ Wob,
                                                 float2* __restrict__ cs)
{
    if (blockIdx.x >= 4096) {           // cs-table packing: 65536 (t,p) pairs
        int pi = ((blockIdx.x - 4096) * 256 + threadIdx.x) * 8;
#pragma unroll
        for (int u = 0; u < 8; ++u)
            cs[pi + u] = float2{cosb[pi + u], sinb[pi + u]};
        return;
    }
    uint32_t id = blockIdx.x * 256 + threadIdx.x;      // one 16-B dst chunk
    const float* src; bf16* dst; float sc = 1.0f;
    if (id < 524288u) {                                // xb: 32rb x 16kb x 1024
        uint32_t tile = id >> 10, slot = id & 1023;
        uint32_t row = (tile >> 4) * 128 + (slot >> 9) * 64 +
                       ((slot >> 6) & 3) * 16 + (slot & 15);
        uint32_t k = (tile & 15) * 64 + ((slot >> 8) & 1) * 32 + ((slot >> 4) & 3) * 8;
        src = x + (size_t)row * 1024 + k;
        dst = xb + (size_t)id * 8;
    } else if (id < 917504u) {                         // Wqkv: 24cb x 16kb x 1024
        uint32_t t2 = id - 524288u;
        uint32_t tile = t2 >> 10, slot = t2 & 1023;
        uint32_t n = (tile >> 4) * 128 + (slot >> 9) * 64 +
                     ((slot >> 6) & 3) * 16 + (slot & 15);
        uint32_t k = (tile & 15) * 64 + ((slot >> 8) & 1) * 32 + ((slot >> 4) & 3) * 8;
        if (n < 1024)      { src = Wq + (size_t)n * 1024 + k;
                             sc = 0.125f * 1.44269504088896f; }
        else if (n < 2048)   src = Wk + (size_t)(n - 1024) * 1024 + k;
        else                 src = Wv + (size_t)(n - 2048) * 1024 + k;
        dst = Wqkv + (size_t)t2 * 8;
    } else {                                           // Wob: 16cb x 16kb x 512
        uint32_t t3 = id - 917504u;
        uint32_t tile = t3 >> 9, slot = t3 & 511;
        uint32_t n = (tile >> 4) * 64 + (slot >> 8) * 32 +
                     ((slot >> 6) & 1) * 16 + (slot & 15);
        uint32_t k = (tile & 15) * 64 + ((slot >> 7) & 1) * 32 + ((slot >> 4) & 3) * 8;
        src = Wo + (size_t)n * 1024 + k;
        dst = Wob + (size_t)t3 * 8;
    }
    float4 v0 = *(const float4*)(src);
    float4 v1 = *(const float4*)(src + 4);
    bf16x8 t;
    t[0] = (bf16)(v0.x*sc); t[1] = (bf16)(v0.y*sc); t[2] = (bf16)(v0.z*sc); t[3] = (bf16)(v0.w*sc);
    t[4] = (bf16)(v1.x*sc); t[5] = (bf16)(v1.y*sc); t[6] = (bf16)(v1.z*sc); t[7] = (bf16)(v1.w*sc);
    *(bf16x8*)dst = t;
}

// ---- QKV GEMM [4096x3072x1024], swizzled-tile inputs, RoPE/Vt epilogue ----
__global__ __launch_bounds__(256) void gemm_qkv(const bf16* __restrict__ A,
                                                const bf16* __restrict__ W,
                                                bf16* __restrict__ QK,
                                                bf16* __restrict__ Vt,
                                                const float2* __restrict__ cs)
{
    __shared__ bf16 As[8192];
    __shared__ bf16 Ws[8192];
    const int tid  = threadIdx.x;
    const int lane = tid & 63, wave = tid >> 6;
    const int rhw = wave >> 1, chw = wave & 1;
    const int wr = rhw * 64, wc = chw * 64;
    const int l16 = lane & 15, lq = lane >> 4;
    const int row0 = blockIdx.x * 128, col0 = blockIdx.y * 128;

    f32x4 acc[4][4];
#pragma unroll
    for (int i = 0; i < 4; ++i)
#pragma unroll
        for (int j = 0; j < 4; ++j) acc[i][j] = f32x4{0.f, 0.f, 0.f, 0.f};

    const bf16* At = A + (size_t)blockIdx.x * 16 * 8192;
    const bf16* Wt = W + (size_t)blockIdx.y * 16 * 8192;

    for (int kb = 0; kb < 16; ++kb) {
        const bf16* at = At + kb * 8192;
        const bf16* wt = Wt + kb * 8192;
#pragma unroll
        for (int rnd = 0; rnd < 4; ++rnd) {
            const int seg = rnd * 4 + wave;            // contiguous 1KB segment
            GLOAD_LDS16(at + seg * 512 + lane * 8, &As[seg * 512]);
            GLOAD_LDS16(wt + seg * 512 + lane * 8, &Ws[seg * 512]);
        }
        __syncthreads();
#pragma unroll
        for (int ks = 0; ks < 2; ++ks) {
            bf16x8 af[4], bfr[4];
#pragma unroll
            for (int i = 0; i < 4; ++i)
                af[i] = *(const bf16x8*)(&As[(rhw * 512 + ks * 256 + i * 64 + lq * 16 + l16) * 8]);
#pragma unroll
            for (int j = 0; j < 4; ++j)
                bfr[j] = *(const bf16x8*)(&Ws[(chw * 512 + ks * 256 + j * 64 + lq * 16 + l16) * 8]);
#pragma unroll
            for (int i = 0; i < 4; ++i)
#pragma unroll
                for (int j = 0; j < 4; ++j)
                    acc[i][j] = __builtin_amdgcn_mfma_f32_16x16x32_bf16(
                        af[i], bfr[j], acc[i][j], 0, 0, 0);
        }
        __syncthreads();
    }

    const int c2 = l16 & 3, g4 = (l16 >> 2) * 4;
    if (blockIdx.y < 16) {
        // Q/K tile: quad-transpose -> lane owns 1 row x 4 cols; RoPE intra-lane
#pragma unroll
        for (int i = 0; i < 4; ++i)
#pragma unroll
            for (int j = 0; j < 4; ++j) {
                float v0 = acc[i][j][0], v1 = acc[i][j][1];
                float v2 = acc[i][j][2], v3 = acc[i][j][3];
                QUAD_T(v0, v1, v2, v3, c2);
                const int row = row0 + wr + i * 16 + lq * 4 + c2;
                const int t   = row & (Tt - 1);
                const int colb = wc + j * 16 + g4;
                const int p0   = (colb & 63) >> 1;
                float4 cp = *(const float4*)(&cs[t * 32 + p0]);  // (c0,s0,c1,s1)
                bf16x4 pk;
                pk[0] = (bf16)(v0 * cp.x - v1 * cp.y);
                pk[1] = (bf16)(v0 * cp.y + v1 * cp.x);
                pk[2] = (bf16)(v2 * cp.z - v3 * cp.w);
                pk[3] = (bf16)(v2 * cp.w + v3 * cp.z);
                *(bf16x4*)(&QK[(size_t)row * 2048 + col0 + colb]) = pk;
            }
    } else {
        // V tile: transposed store into Vt[bh][d][t]
#pragma unroll
        for (int i = 0; i < 4; ++i)
#pragma unroll
            for (int j = 0; j < 4; ++j) {
                const int dfull = col0 - 2048 + wc + j * 16 + l16;
                const int h = dfull >> 6, d = dfull & 63;
                const int row = row0 + wr + i * 16 + lq * 4;
                const int b = row >> 11, t = row & (Tt - 1);
                bf16x4 pk;
                pk[0] = (bf16)acc[i][j][0]; pk[1] = (bf16)acc[i][j][1];
                pk[2] = (bf16)acc[i][j][2]; pk[3] = (bf16)acc[i][j][3];
                *(bf16x4*)(&Vt[((size_t)(b * 16 + h) * 64 + d) * (size_t)Tt + t]) = pk;
            }
    }
}

// ---- O GEMM: 128x64 tiles, swizzled A (from attn) + swizzled Wob, fp32 out --
__global__ __launch_bounds__(256) void gemm_o(const bf16* __restrict__ A,
                                              const bf16* __restrict__ W,
                                              float* __restrict__ Out)
{
    __shared__ bf16 As[8192];
    __shared__ bf16 Ws[4096];
    const int tid  = threadIdx.x;
    const int lane = tid & 63, wave = tid >> 6;
    const int rhw = wave >> 1, chw = wave & 1;
    const int wr = rhw * 64, wc = chw * 32;
    const int l16 = lane & 15, lq = lane >> 4;
    const int row0 = blockIdx.x * 128, col0 = blockIdx.y * 64;

    f32x4 acc[4][2];
#pragma unroll
    for (int i = 0; i < 4; ++i)
#pragma unroll
        for (int j = 0; j < 2; ++j) acc[i][j] = f32x4{0.f, 0.f, 0.f, 0.f};

    const bf16* At = A + (size_t)blockIdx.x * 16 * 8192;
    const bf16* Wt = W + (size_t)blockIdx.y * 16 * 4096;

    for (int kb = 0; kb < 16; ++kb) {
        const bf16* at = At + kb * 8192;
        const bf16* wt = Wt + kb * 4096;
#pragma unroll
        for (int rnd = 0; rnd < 4; ++rnd) {
            const int seg = rnd * 4 + wave;
            GLOAD_LDS16(at + seg * 512 + lane * 8, &As[seg * 512]);
        }
#pragma unroll
        for (int rnd = 0; rnd < 2; ++rnd) {
            const int seg = rnd * 4 + wave;
            GLOAD_LDS16(wt + seg * 512 + lane * 8, &Ws[seg * 512]);
        }
        __syncthreads();
#pragma unroll
        for (int ks = 0; ks < 2; ++ks) {
            bf16x8 af[4], bfr[2];
#pragma unroll
            for (int i = 0; i < 4; ++i)
                af[i] = *(const bf16x8*)(&As[(rhw * 512 + ks * 256 + i * 64 + lq * 16 + l16) * 8]);
#pragma unroll
            for (int j = 0; j < 2; ++j)
                bfr[j] = *(const bf16x8*)(&Ws[(chw * 256 + ks * 128 + j * 64 + lq * 16 + l16) * 8]);
#pragma unroll
            for (int i = 0; i < 4; ++i)
#pragma unroll
                for (int j = 0; j < 2; ++j)
                    acc[i][j] = __builtin_amdgcn_mfma_f32_16x16x32_bf16(
                        af[i], bfr[j], acc[i][j], 0, 0, 0);
        }
        __syncthreads();
    }
    const int c2 = l16 & 3, g4 = (l16 >> 2) * 4;
#pragma unroll
    for (int i = 0; i < 4; ++i)
#pragma unroll
        for (int j = 0; j < 2; ++j) {
            float v0 = acc[i][j][0], v1 = acc[i][j][1];
            float v2 = acc[i][j][2], v3 = acc[i][j][3];
            QUAD_T(v0, v1, v2, v3, c2);
            const int row = row0 + wr + i * 16 + lq * 4 + c2;
            const int col = col0 + wc + j * 16 + g4;
            *(float4*)(&Out[(size_t)row * Cc + col]) = float4{v0, v1, v2, v3};
        }
}

// ---- MFMA flash attention, 32x32x16 shape, QBLK=64, 256 threads = 4 waves:
// wave (kh,qh) owns q-cols qh*32+[0,32) x keys kh*32+[0,32) of each 64-key
// step. 4 blocks/CU = 16 waves/CU. dbuf LDS 1 barrier/step, R12 qt map,
// named regs only. End-of-block cross-kh combine via f32 scratch in dead Ks.
__global__ __launch_bounds__(256, 4) void attn_k(const bf16* __restrict__ QK,
                                                 const bf16* __restrict__ Vt,
                                                 bf16* __restrict__ O)
{
    __shared__ bf16 Ks[2][64 * LDS_];
    __shared__ bf16 Vs[2][64 * LDS_];
    const int tid = threadIdx.x;
    const int wv = tid >> 6, lane = tid & 63;
    const int l31 = lane & 31, hf = lane >> 5;
    const int qh = wv & 1, kh = wv >> 1;
    // grid (32,32)=1024 blocks, 4/CU. id&7 ~ XCD; 4 bh per XCD.
    // Rounds rnd4=id>>8 give qt = {31-s,16+s,15-s,s}: every CU's 4 resident
    // blocks sum to (32-s)+(17+s)+(16-s)+(1+s) = 66 key-steps.
    const int id = blockIdx.y * gridDim.x + blockIdx.x;
    const int bh = (id & 7) * 4 + ((id >> 3) & 3);
    const int s8 = (id >> 5) & 7, rnd4 = id >> 8;
    const int qt = (rnd4 == 0) ? 31 - s8 : (rnd4 == 1) ? 16 + s8
                 : (rnd4 == 2) ? 15 - s8 : s8;
    const int b = bh >> 4, h = bh & 15;
    const int kr = tid >> 2, c0 = (tid & 3) * 16;       // staging coords

    const bf16* kcol = QK + 1024 + (size_t)(b * Tt + kr) * 2048 + h * 64 + c0;
    const bf16* vcol = Vt + ((size_t)bh * 64 + kr) * Tt + c0;

    // Q B-frags: lane = q-col (l31) of this wave's 32; k(d) = 16*kc + 8*hf + j
    const int qglob = qt * 64 + qh * 32 + l31;
    const bf16* qp = QK + (size_t)(b * Tt + qglob) * 2048 + h * 64 + hf * 8;
    const bf16x8 qf0 = *(const bf16x8*)(qp);
    const bf16x8 qf1 = *(const bf16x8*)(qp + 16);
    const bf16x8 qf2 = *(const bf16x8*)(qp + 32);
    const bf16x8 qf3 = *(const bf16x8*)(qp + 48);

    // prologue: tile 0 -> named regs -> buf 0 (Ks[key][d], Vs[d][key])
    uint4 ka0 = *(const uint4*)(kcol);
    uint4 ka1 = *(const uint4*)(kcol + 8);
    uint4 va0 = *(const uint4*)(vcol);
    uint4 va1 = *(const uint4*)(vcol + 8);
    {
        bf16* kd = &Ks[0][kr * LDS_ + c0];
        bf16* vd = &Vs[0][kr * LDS_ + c0];
        *(uint4*)(kd)     = ka0; *(uint4*)(kd + 8) = ka1;
        *(uint4*)(vd)     = va0; *(uint4*)(vd + 8) = va1;
    }
    __syncthreads();

    float la = 0.f, lb = 0.f;
    f32x16 o0, o1;
#pragma unroll
    for (int r = 0; r < 16; ++r) { o0[r] = 0.f; o1[r] = 0.f; }

    for (int t = 0; t <= qt; ++t) {
        const int cur = t & 1;
        if (t < qt) {                   // prefetch next tile into named regs
            const bf16* kn = kcol + (size_t)(t + 1) * 64 * 2048;
            const bf16* vn = vcol + (t + 1) * 64;
            ka0 = *(const uint4*)(kn); ka1 = *(const uint4*)(kn + 8);
            va0 = *(const uint4*)(vn); va1 = *(const uint4*)(vn + 8);
        }

        // S^T tile: keys kh*32+[0,32) x q. A = K rows, B = qf0..3 (K-dim 64)
        f32x16 s;
#pragma unroll
        for (int r = 0; r < 16; ++r) s[r] = 0.f;
        {
            const bf16* kb = &Ks[cur][(kh * 32 + l31) * LDS_ + hf * 8];
            bf16x8 a;
            a = *(const bf16x8*)(kb);      s = __builtin_amdgcn_mfma_f32_32x32x16_bf16(a, qf0, s, 0, 0, 0);
            a = *(const bf16x8*)(kb + 16); s = __builtin_amdgcn_mfma_f32_32x32x16_bf16(a, qf1, s, 0, 0, 0);
            a = *(const bf16x8*)(kb + 32); s = __builtin_amdgcn_mfma_f32_32x32x16_bf16(a, qf2, s, 0, 0, 0);
            a = *(const bf16x8*)(kb + 48); s = __builtin_amdgcn_mfma_f32_32x32x16_bf16(a, qf3, s, 0, 0, 0);
        }
        if (t == qt) {                  // causal mask, diagonal tile only
            const int kbase = t * 64 + kh * 32 + 4 * hf;
#pragma unroll
            for (int r = 0; r < 16; ++r) {
                const int key0 = kbase + (r & 3) + 8 * (r >> 2);
                if (key0 > qglob) s[r] = -1e30f;
            }
        }
        // exp2 (inline-asm v_exp_f32) + scalar partial sums (lane covers its
        // key-half's key%8 in [4hf,4hf+3]; partner hf has the rest ->
        // shfl_xor(32) at the end)
#pragma unroll
        for (int r = 0; r < 16; ++r) {
            s[r] = ex2(s[r]);
            if (r & 1) lb += s[r]; else la += s[r];
        }
        // P^T C-frag -> PV B-frags (keys kh*32+16c+8hf+j): cvt_pk + permlane
        bf16x8 pb0, pb1;
        {
            unsigned X, Y, Z, W;
            union { unsigned u[4]; bf16x8 h; } tmp;
            X = pkb(s[0],  s[1]);  Y = pkb(s[2],  s[3]);
            Z = pkb(s[4],  s[5]);  W = pkb(s[6],  s[7]);
            asm("v_permlane32_swap_b32 %0, %1" : "+v"(X), "+v"(Z));
            asm("v_permlane32_swap_b32 %0, %1" : "+v"(Y), "+v"(W));
            tmp.u[0] = X; tmp.u[1] = Y; tmp.u[2] = Z; tmp.u[3] = W; pb0 = tmp.h;
            X = pkb(s[8],  s[9]);  Y = pkb(s[10], s[11]);
            Z = pkb(s[12], s[13]); W = pkb(s[14], s[15]);
            asm("v_permlane32_swap_b32 %0, %1" : "+v"(X), "+v"(Z));
            asm("v_permlane32_swap_b32 %0, %1" : "+v"(Y), "+v"(W));
            tmp.u[0] = X; tmp.u[1] = Y; tmp.u[2] = Z; tmp.u[3] = W; pb1 = tmp.h;
        }
        // O^T partial += V^T[d, kh-keys] P^T : A = Vs rows (d), cols kh*32+..
        {
            const bf16* vb0 = &Vs[cur][l31 * LDS_ + kh * 32 + hf * 8];
            const bf16* vb1 = &Vs[cur][(32 + l31) * LDS_ + kh * 32 + hf * 8];
            bf16x8 v;
            v = *(const bf16x8*)(vb0);      o0 = __builtin_amdgcn_mfma_f32_32x32x16_bf16(v, pb0, o0, 0, 0, 0);
            v = *(const bf16x8*)(vb0 + 16); o0 = __builtin_amdgcn_mfma_f32_32x32x16_bf16(v, pb1, o0, 0, 0, 0);
            v = *(const bf16x8*)(vb1);      o1 = __builtin_amdgcn_mfma_f32_32x32x16_bf16(v, pb0, o1, 0, 0, 0);
            v = *(const bf16x8*)(vb1 + 16); o1 = __builtin_amdgcn_mfma_f32_32x32x16_bf16(v, pb1, o1, 0, 0, 0);
        }
        if (t < qt) {                   // commit prefetched tile to buf^1
            bf16* kd = &Ks[cur ^ 1][kr * LDS_ + c0];
            bf16* vd = &Vs[cur ^ 1][kr * LDS_ + c0];
            *(uint4*)(kd)     = ka0; *(uint4*)(kd + 8) = ka1;
            *(uint4*)(vd)     = va0; *(uint4*)(vd + 8) = va1;
        }
        __syncthreads();                // publish buf^1; all readers done
    }
    float lsum = la + lb;
    lsum += __shfl_xor(lsum, 32);       // combine hf partials (16+16 keys)

    // cross-kh combine: kh=1 writes partial O (64d x 32q f32) + l into dead
    // Ks (16.9KB f32 < 36.8KB) / Vs; kh=0 adds, divides, stores.
    float* fscr = (float*)(&Ks[0][0]);
    float* lscr = (float*)(&Vs[0][0]);
    if (kh == 1) {
        float* sb = fscr + qh * (64 * 33);
#pragma unroll
        for (int r = 0; r < 16; ++r) {
            const int d = (r & 3) + 8 * (r >> 2) + 4 * hf;
            sb[d * 33 + l31]        = o0[r];
            sb[(d + 32) * 33 + l31] = o1[r];
        }
        if (hf == 0) lscr[qh * 32 + l31] = lsum;
    }
    __syncthreads();
    if (kh == 0) {
        const float* sb = fscr + qh * (64 * 33);
#pragma unroll
        for (int r = 0; r < 16; ++r) {
            const int d = (r & 3) + 8 * (r >> 2) + 4 * hf;
            o0[r] += sb[d * 33 + l31];
            o1[r] += sb[(d + 32) * 33 + l31];
        }
        lsum += lscr[qh * 32 + l31];
        const float inv = 1.f / lsum;

        // store O in gemm_o's swizzled A layout.
        // 128-row tile index = qt>>1, rh = qt&1; row128 = rh*64 + qh*32 + l31;
        // d = 32*dt + 8*g + 4*hf + r.
        bf16* obase = O + ((size_t)(16 * b + (qt >> 1)) * 16 + h) * 8192;
        const int rh = qt & 1;
        const int slot_row = (lane & 15) | (((2 * qh + ((lane >> 4) & 1)) & 3) << 6) |
                             (rh << 9);
#pragma unroll
        for (int g = 0; g < 4; ++g) {
            bf16x4 w0, w1;
#pragma unroll
            for (int r = 0; r < 4; ++r) {
                w0[r] = (bf16)(o0[4 * g + r] * inv);
                w1[r] = (bf16)(o1[4 * g + r] * inv);
            }
            *(bf16x4*)(obase + (slot_row | (g << 4)) * 8 + 4 * hf) = w0;
            *(bf16x4*)(obase + (slot_row | (g << 4) | 256) * 8 + 4 * hf) = w1;
        }
    }
}

extern "C" void kernel_launch(void* const* d_in, const int* in_sizes, int n_in,
                              void* d_out, int out_size, void* d_ws, size_t ws_size,
                              hipStream_t stream)
{
    const float* x    = (const float*)d_in[0];
    const float* Wq   = (const float*)d_in[1];
    const float* Wk   = (const float*)d_in[2];
    const float* Wv   = (const float*)d_in[3];
    const float* Wo   = (const float*)d_in[4];
    const float* cosb = (const float*)d_in[5];
    const float* sinb = (const float*)d_in[6];

    constexpr size_t M1 = 1024 * 1024;
    bf16* base = (bf16*)d_ws;
    bf16*   xb   = base;                    //  0..4M   swizzled x; reused attn-out
    bf16*   QK   = base + 4 * M1;           //  4M..12M [4096][2048]
    bf16*   VtG  = base + 12 * M1;          // 12M..16M [32][64][2048]
    bf16*   Wqkv = base + 16 * M1;          // 16M..19M swizzled
    bf16*   Wob  = base + 19 * M1;          // 19M..20M swizzled (64-row tiles)
    float2* csT  = (float2*)(base + 20 * M1); // 512 KB
    bf16*   Ow   = xb;

    convert_k<<<4096 + 32, 256, 0, stream>>>(x, Wq, Wk, Wv, Wo, cosb, sinb,
                                             xb, Wqkv, Wob, csT);

    gemm_qkv<<<dim3(Mrows / 128, 3072 / 128), 256, 0, stream>>>(
        xb, Wqkv, QK, VtG, csT);

    attn_k<<<dim3(32, 32), 256, 0, stream>>>(QK, VtG, Ow);

    gemm_o<<<dim3(Mrows / 128, Cc / 64), 256, 0, stream>>>(Ow, Wob, (float*)d_out);
}